// Round 11
// baseline (125.150 us; speedup 1.0000x reference)
//
#include <hip/hip_runtime.h>
#include <stdint.h>

#define B_ 4
#define N_ 512
#define F_ 64
#define R_ 128
#define PPI 511          // pairs per i = N-1
#define TJ 128           // j's per tile

typedef _Float16 f16x8 __attribute__((ext_vector_type(8)));
typedef _Float16 f16x2 __attribute__((ext_vector_type(2)));
typedef float f32x4 __attribute__((ext_vector_type(4)));

__device__ __forceinline__ uint16_t f16bits(float x) {
  return __builtin_bit_cast(uint16_t, (_Float16)x);
}
__device__ __forceinline__ f16x2 cvt_pk(float a, float b) {
  return __builtin_bit_cast(f16x2, __builtin_amdgcn_cvt_pkrtz(a, b));
}

// ---------------- fused prep (R9 version: 2x parallelism) ----------------
__global__ __launch_bounds__(256) void prep_all(
    const float* __restrict__ feat, const float* __restrict__ W1,
    const float* __restrict__ b1, const float* __restrict__ W2,
    uint16_t* __restrict__ U, uint16_t* __restrict__ V, uint16_t* __restrict__ w2f) {
  if (blockIdx.x >= 1024) {
    const int d = (blockIdx.x - 1024) * 256 + threadIdx.x;  // 0..16383
    const int jj = d & 7, lane = (d >> 3) & 63, tc = d >> 9;
    const int c = tc & 3, t = tc >> 2;
    const int rr = 32 * c + (lane >> 4) * 8 + jj;
    const int s = 16 * t + (lane & 15);
    w2f[d] = f16bits(W2[rr * R_ + s]);
    return;
  }
  __shared__ float fs[2][F_];
  const int row0 = blockIdx.x * 2;  // global row = b*N_ + i
  const int tid = threadIdx.x;
  if (tid < 2 * F_) fs[tid >> 6][tid & 63] = feat[row0 * F_ + tid];
  __syncthreads();
  const int r = tid & 127, rh = tid >> 7;
  const int row = row0 + rh;
  float u0 = b1[r], u1 = 0.f, v0 = 0.f, v1 = 0.f;
#pragma unroll
  for (int f = 0; f < F_; f += 2) {
    const float x0 = fs[rh][f], x1 = fs[rh][f + 1];
    u0 = fmaf(x0, W1[f * R_ + r], u0);
    v0 = fmaf(x0, W1[(F_ + f) * R_ + r], v0);
    u1 = fmaf(x1, W1[(f + 1) * R_ + r], u1);
    v1 = fmaf(x1, W1[(F_ + f + 1) * R_ + r], v1);
  }
  U[row * R_ + r] = f16bits(u0 + u1);
  V[row * R_ + r] = f16bits(v0 + v1);
}

// ---------------- Main fused kernel ----------------
// R11 PERSISTENT TILES + DOUBLE-BUFFERED STAGE (T14 issue-early/write-late):
// grid B_ * (N_/2) = 1024 blocks of 256 threads. Block = (b, i0-pair),
// loops over all 4 j-tiles. Rationale: TLP axis exhausted (R2 VALU-trim
// null, R10 +36% occupancy null, R3/R7 restructures worse); measured dur
// (42-46us) is ~2x the MFMA+VALU issue demand (~21us) -> per-tile serial
// phases (w2r/uf prologue reloads, stage->barrier latency exposure) are
// the remaining cost. Fix: w2r/w3p/uf/b2f loaded ONCE per block (was 4x);
// Vs double-buffered (2x32KB) with next tile's global loads ISSUED BEFORE
// compute of the current tile (reg-staged), ds_write after compute, one
// barrier covers pl+buf. LDS 73728 -> 2 blocks/CU = 8 waves/CU: same
// occupancy as today, isolating stall-removal. launch_bounds (256,2):
// reg cap 256, need ~184 unified (120 VGPR + 64 AGPR w2r) -> no spill.
__global__ __launch_bounds__(256, 2) void relnet_main(
    const uint16_t* __restrict__ U, const uint16_t* __restrict__ V,
    const uint16_t* __restrict__ w2f, const float* __restrict__ b2,
    const float* __restrict__ W3, const float* __restrict__ b3,
    float* __restrict__ out) {
  // [0,65536): Vs double buffer (2 x 128 rows x 256B, swizzled)
  // [65536,73728): pl reduction buffer [th][il][jt][quad][l4]
  __shared__ __align__(16) uint8_t smem[73728];
  float* const pl = (float*)(smem + 65536);

  const int bid = blockIdx.x;           // 0..1023
  const int ib = bid & 255, b = bid >> 8;
  const int i0 = ib * 2;
  const int tid = threadIdx.x;
  const int lane = tid & 63, wave = tid >> 6;
  const int quad = lane >> 4, l4 = lane & 15;
  const int il = wave >> 1, th = wave & 1;
  const int i = i0 + il;

  // ---- per-block loop-invariant state (loaded ONCE) ----
  // this wave's half of W2^T A-frags (t = th*4 + t'): 16 frags = 64 regs
  f16x8 w2r[4][4];
#pragma unroll
  for (int tp = 0; tp < 4; ++tp)
#pragma unroll
    for (int c = 0; c < 4; ++c) {
      const int t = th * 4 + tp;
      const uint4 w = *(const uint4*)(w2f + ((size_t)((t * 4 + c) * 64 + lane)) * 8);
      w2r[tp][c] = __builtin_bit_cast(f16x8, w);
    }

  // b2 as MFMA C-init; W3 packed fp16 for fdot2
  f32x4 b2f[4];
  f16x2 w3p[4][2];
#pragma unroll
  for (int tp = 0; tp < 4; ++tp) {
    const int s0 = 16 * (th * 4 + tp) + 4 * quad;
    b2f[tp] = (f32x4){b2[s0], b2[s0 + 1], b2[s0 + 2], b2[s0 + 3]};
    w3p[tp][0] = (f16x2){(_Float16)W3[s0], (_Float16)W3[s0 + 1]};
    w3p[tp][1] = (f16x2){(_Float16)W3[s0 + 2], (_Float16)W3[s0 + 3]};
  }

  // u' frag for this wave's i (loop-invariant across all 4 tiles)
  f16x8 uf[4];
#pragma unroll
  for (int c = 0; c < 4; ++c)
    uf[c] = __builtin_bit_cast(f16x8,
        *(const uint4*)(U + (size_t)(b * N_ + i) * R_ + c * 32 + quad * 8));

  const float bias3 = b3[0];
  const f16x8 z8 = {};
  const f16x2 z2 = {};

  const uint4* const Vb = (const uint4*)(V + (size_t)(b * N_) * R_);  // uint4 units

  // ---- prologue: stage tile 0 into buf0 ----
  uint4 st[8];
#pragma unroll
  for (int k = 0; k < 8; ++k) st[k] = Vb[tid + 256 * k];
#pragma unroll
  for (int k = 0; k < 8; ++k) {
    const int l = tid + 256 * k, row = l >> 4, seg = l & 15;
    *(uint4*)(smem + row * 256 + ((seg * 16) ^ ((row & 7) << 4))) = st[k];
  }
  __syncthreads();

  int curoff = 0;
  for (int jb = 0; jb < 4; ++jb) {
    // issue next tile's global loads FIRST (latency hides under compute)
    if (jb < 3) {
      const uint4* src = Vb + (size_t)(jb + 1) * TJ * (R_ / 8);
#pragma unroll
      for (int k = 0; k < 8; ++k) st[k] = src[tid + 256 * k];
    }

    const uint8_t* const buf = smem + curoff;

    // ---- compute current tile ----
#pragma unroll
    for (int jt = 0; jt < 8; ++jt) {
      // h1 B-frags: B[k = 32c + quad*8 + jj][n = l4] = relu(u'[k] + v_j[k])
      f16x8 hb[4];
#pragma unroll
      for (int c = 0; c < 4; ++c) {
        const uint4 v = *(const uint4*)(buf + (jt * 16 + l4) * 256 +
                                        ((c * 64 + quad * 16) ^ ((l4 & 7) << 4)));
        hb[c] = __builtin_elementwise_max(__builtin_bit_cast(f16x8, v) + uf[c], z8);
      }

      // layer2 MFMA; first k-slice consumes b2f directly as C
      f32x4 acc[4];
      __builtin_amdgcn_s_setprio(1);
#pragma unroll
      for (int tp = 0; tp < 4; ++tp)
        acc[tp] = __builtin_amdgcn_mfma_f32_16x16x32_f16(w2r[tp][0], hb[0], b2f[tp], 0, 0, 0);
#pragma unroll
      for (int c = 1; c < 4; ++c)
#pragma unroll
        for (int tp = 0; tp < 4; ++tp)
          acc[tp] = __builtin_amdgcn_mfma_f32_16x16x32_f16(w2r[tp][c], hb[c], acc[tp], 0, 0, 0);
      __builtin_amdgcn_s_setprio(0);

      // layer3 in-lane partial: relu + fp16 dot
      float t0 = 0.f, t1 = 0.f, t2 = 0.f, t3 = 0.f;
#pragma unroll
      for (int tp = 0; tp < 4; tp += 2) {
        f16x2 p0 = __builtin_elementwise_max(cvt_pk(acc[tp][0], acc[tp][1]), z2);
        f16x2 p1 = __builtin_elementwise_max(cvt_pk(acc[tp][2], acc[tp][3]), z2);
        t0 = __builtin_amdgcn_fdot2(p0, w3p[tp][0], t0, false);
        t1 = __builtin_amdgcn_fdot2(p1, w3p[tp][1], t1, false);
        f16x2 q0 = __builtin_elementwise_max(cvt_pk(acc[tp + 1][0], acc[tp + 1][1]), z2);
        f16x2 q1 = __builtin_elementwise_max(cvt_pk(acc[tp + 1][2], acc[tp + 1][3]), z2);
        t2 = __builtin_amdgcn_fdot2(q0, w3p[tp + 1][0], t2, false);
        t3 = __builtin_amdgcn_fdot2(q1, w3p[tp + 1][1], t3, false);
      }
      // conflict-free per-jt store (64 consecutive dwords per wave-quad set)
      pl[(((th * 2 + il) * 8) + jt) * 64 + quad * 16 + l4] = (t0 + t1) + (t2 + t3);
    }

    // write next tile into the other buffer (loads long since landed)
    if (jb < 3) {
      uint8_t* const nbuf = smem + (curoff ^ 32768);
#pragma unroll
      for (int k = 0; k < 8; ++k) {
        const int l = tid + 256 * k, row = l >> 4, seg = l & 15;
        *(uint4*)(nbuf + row * 256 + ((seg * 16) ^ ((row & 7) << 4))) = st[k];
      }
    }

    __syncthreads();  // pl ready for tail; next buf ready for next iter

    // ---- tail for this tile ----
    {
      const int ril = tid >> 7, rjt = (tid >> 4) & 7, rl4 = tid & 15;
      float sum = bias3;
#pragma unroll
      for (int h = 0; h < 2; ++h)
#pragma unroll
        for (int q = 0; q < 4; ++q)
          sum += pl[((h * 2 + ril) * 8 + rjt) * 64 + q * 16 + rl4];
      const int ri = i0 + ril;
      const int j = jb * TJ + rjt * 16 + rl4;
      if (j != ri) {
        const int p = (b * N_ + ri) * PPI + (j < ri ? j : j - 1);
        out[p] = sum;
      }
    }

    __syncthreads();  // tail's pl reads done before next tile overwrites
    curoff ^= 32768;
  }
}

extern "C" void kernel_launch(void* const* d_in, const int* in_sizes, int n_in,
                              void* d_out, int out_size, void* d_ws, size_t ws_size,
                              hipStream_t stream) {
  const float* feat = (const float*)d_in[0];
  const float* W1 = (const float*)d_in[1];
  const float* b1 = (const float*)d_in[2];
  const float* W2 = (const float*)d_in[3];
  const float* b2 = (const float*)d_in[4];
  const float* W3 = (const float*)d_in[5];
  const float* b3 = (const float*)d_in[6];

  uint16_t* U = (uint16_t*)d_ws;                 // B*N*R fp16 = 512 KiB
  uint16_t* V = U + (size_t)B_ * N_ * R_;        // 512 KiB
  uint16_t* w2f = V + (size_t)B_ * N_ * R_;      // 32 KiB

  prep_all<<<1024 + 64, 256, 0, stream>>>(feat, W1, b1, W2, U, V, w2f);
  relnet_main<<<B_ * (N_ / 2), 256, 0, stream>>>(U, V, w2f, b2, W3, b3,
                                                 (float*)d_out);
}

// Round 12
// 109.183 us; speedup vs baseline: 1.1462x; 1.1462x over previous
//
#include <hip/hip_runtime.h>
#include <stdint.h>

#define B_ 4
#define N_ 512
#define F_ 64
#define R_ 128
#define PPI 511          // pairs per i = N-1
#define TJ 128           // j's per block

typedef _Float16 f16x8 __attribute__((ext_vector_type(8)));
typedef _Float16 f16x2 __attribute__((ext_vector_type(2)));
typedef float f32x4 __attribute__((ext_vector_type(4)));

__device__ __forceinline__ uint16_t f16bits(float x) {
  return __builtin_bit_cast(uint16_t, (_Float16)x);
}
__device__ __forceinline__ f16x2 cvt_pk(float a, float b) {
  return __builtin_bit_cast(f16x2, __builtin_amdgcn_cvt_pkrtz(a, b));
}

// ---------------- fused prep (R12: LDS-resident W1, 32 rows/block) --------
// Old prep was latency/L2-bound: W1 reuse/block = 2x -> 134 MB of L2 reads,
// each thread 128 batched L2 loads (~7-8 us). Now: 64 blocks x 32 rows;
// W1 staged ONCE per block into LDS (64 KB; W1 traffic 134 MB -> 4 MB),
// feat staged TRANSPOSED (featT[f][row], stride 36 -> b128 = 4 rows).
// Thread owns r = tid&127, rh = tid>>7 -> 16 rows. Per f: 2 stride-1
// ds_read_b32 (W1 col, conflict-free) + 4 broadcast ds_read_b128 (feat)
// + 32 fmaf -> issue-bound ~2 us/block, all blocks concurrent.
// blocks [64,128): pack W2^T into fp16 A-fragment order (unchanged math):
//   dst[((t*4+c)*64+lane)*8+jj] = W2[(32c+(lane>>4)*8+jj)*R + 16t+(lane&15)]
__global__ __launch_bounds__(256) void prep_all(
    const float* __restrict__ feat, const float* __restrict__ W1,
    const float* __restrict__ b1, const float* __restrict__ W2,
    uint16_t* __restrict__ U, uint16_t* __restrict__ V, uint16_t* __restrict__ w2f) {
  if (blockIdx.x >= 64) {
    const int d = (blockIdx.x - 64) * 256 + threadIdx.x;  // 0..16383
    const int jj = d & 7, lane = (d >> 3) & 63, tc = d >> 9;
    const int c = tc & 3, t = tc >> 2;
    const int rr = 32 * c + (lane >> 4) * 8 + jj;
    const int s = 16 * t + (lane & 15);
    w2f[d] = f16bits(W2[rr * R_ + s]);
    return;
  }
  __shared__ __align__(16) float W1s[2 * F_ * R_];  // [f][r], 64 KiB
  __shared__ __align__(16) float fT[F_ * 36];       // featT[f][row], stride 36

  const int tid = threadIdx.x;
  const int row0 = blockIdx.x * 32;  // global row in [0, 2048)

  // stage W1 (16384 f32 = 4096 uint4, coalesced, linear)
  {
    const uint4* s = (const uint4*)W1;
    uint4* d = (uint4*)W1s;
#pragma unroll
    for (int k = 0; k < 16; ++k) d[tid + 256 * k] = s[tid + 256 * k];
  }
  // stage feat transposed: thread loads 8 consecutive f of one row
  {
    const float4* fs = (const float4*)(feat + (size_t)row0 * F_);
    const float4 a = fs[tid * 2];
    const float4 b = fs[tid * 2 + 1];
    const int row = tid >> 3, f0 = (tid & 7) * 8;
    fT[(f0 + 0) * 36 + row] = a.x;
    fT[(f0 + 1) * 36 + row] = a.y;
    fT[(f0 + 2) * 36 + row] = a.z;
    fT[(f0 + 3) * 36 + row] = a.w;
    fT[(f0 + 4) * 36 + row] = b.x;
    fT[(f0 + 5) * 36 + row] = b.y;
    fT[(f0 + 6) * 36 + row] = b.z;
    fT[(f0 + 7) * 36 + row] = b.w;
  }
  __syncthreads();

  const int r = tid & 127, rh = tid >> 7;  // rh -> rows rh*16 .. rh*16+15
  float u[16], v[16];
  const float bias = b1[r];
#pragma unroll
  for (int j = 0; j < 16; ++j) { u[j] = bias; v[j] = 0.f; }

#pragma unroll 4
  for (int f = 0; f < F_; ++f) {
    const float wa = W1s[f * R_ + r];
    const float wb = W1s[(F_ + f) * R_ + r];
    const f32x4 x0 = *(const f32x4*)&fT[f * 36 + rh * 16 + 0];
    const f32x4 x1 = *(const f32x4*)&fT[f * 36 + rh * 16 + 4];
    const f32x4 x2 = *(const f32x4*)&fT[f * 36 + rh * 16 + 8];
    const f32x4 x3 = *(const f32x4*)&fT[f * 36 + rh * 16 + 12];
#pragma unroll
    for (int k = 0; k < 4; ++k) {
      u[0 + k] = fmaf(x0[k], wa, u[0 + k]);
      v[0 + k] = fmaf(x0[k], wb, v[0 + k]);
      u[4 + k] = fmaf(x1[k], wa, u[4 + k]);
      v[4 + k] = fmaf(x1[k], wb, v[4 + k]);
      u[8 + k] = fmaf(x2[k], wa, u[8 + k]);
      v[8 + k] = fmaf(x2[k], wb, v[8 + k]);
      u[12 + k] = fmaf(x3[k], wa, u[12 + k]);
      v[12 + k] = fmaf(x3[k], wb, v[12 + k]);
    }
  }

#pragma unroll
  for (int j = 0; j < 16; ++j) {
    const int row = row0 + rh * 16 + j;
    U[(size_t)row * R_ + r] = f16bits(u[j]);
    V[(size_t)row * R_ + r] = f16bits(v[j]);
  }
}

// ---------------- Main fused kernel (byte-identical to R9/R6 best) --------
// grid: B_ * (N_/2) * (N_/TJ) = 4096 blocks of 256 threads (4 waves).
// Block = (b, i0..i0+1, j0..j0+127). Wave w: il = w>>1, th = w&1.
// Design-space map (R1-R11): this structure is a sharp local optimum
// (~42 us): +occupancy null (R10), -occupancy worse (R3), no-LDS worse
// (R8), persistence+dbuf spills (R11), VALU trims null (R2). MfmaUtil+
// VALUBusy ~77% -> issue/pipe budget near-saturated for this mix.
__global__ __launch_bounds__(256, 3) void relnet_main(
    const uint16_t* __restrict__ U, const uint16_t* __restrict__ V,
    const uint16_t* __restrict__ w2f, const float* __restrict__ b2,
    const float* __restrict__ W3, const float* __restrict__ b3,
    float* __restrict__ out) {
  // 32768 B total. During loop: swizzled V rows. After loop: reduction buf
  // pls[th][il][jt][quad][l4] (2048 floats = 8192 B) overlaid on the front.
  __shared__ __align__(16) uint16_t Vs[TJ * 128];

  const int bid = blockIdx.x;
  const int jb = bid & 3, ib = (bid >> 2) & 255, b = bid >> 10;
  const int i0 = ib * 2, j0 = jb * TJ;
  const int tid = threadIdx.x;

  // stage V rows j0..j0+127 (fp16, swizzled 16B slots within 256B rows)
  {
    const uint4* sv = (const uint4*)(V + (b * N_ + j0) * R_);
    for (int l = tid; l < TJ * 16; l += 256) {
      const int row = l >> 4, seg = l & 15;
      const int col = (seg * 16) ^ ((row & 7) << 4);
      *(uint4*)((char*)Vs + row * 256 + col) = sv[row * 16 + seg];
    }
  }

  const int lane = tid & 63, wave = tid >> 6;
  const int quad = lane >> 4, l4 = lane & 15;
  const int il = wave >> 1, th = wave & 1;
  const int i = i0 + il;

  // this wave's half of W2^T A-frags (t = th*4 + t'): 16 frags = 64 regs
  f16x8 w2r[4][4];
#pragma unroll
  for (int tp = 0; tp < 4; ++tp)
#pragma unroll
    for (int c = 0; c < 4; ++c) {
      const int t = th * 4 + tp;
      const uint4 w = *(const uint4*)(w2f + ((size_t)((t * 4 + c) * 64 + lane)) * 8);
      w2r[tp][c] = __builtin_bit_cast(f16x8, w);
    }

  // epilogue constants for this t-half: s = 16t + 4*quad + reg
  // b2 enters as the C operand of the first MFMA (fp32 exact); W3 packed fp16
  f32x4 b2f[4];
  f16x2 w3p[4][2];
#pragma unroll
  for (int tp = 0; tp < 4; ++tp) {
    const int s0 = 16 * (th * 4 + tp) + 4 * quad;
    b2f[tp] = (f32x4){b2[s0], b2[s0 + 1], b2[s0 + 2], b2[s0 + 3]};
    w3p[tp][0] = (f16x2){(_Float16)W3[s0], (_Float16)W3[s0 + 1]};
    w3p[tp][1] = (f16x2){(_Float16)W3[s0 + 2], (_Float16)W3[s0 + 3]};
  }

  // u' frag for this wave's i, straight from global (loop-invariant)
  f16x8 uf[4];
#pragma unroll
  for (int c = 0; c < 4; ++c)
    uf[c] = __builtin_bit_cast(f16x8,
        *(const uint4*)(U + (size_t)(b * N_ + i) * R_ + c * 32 + quad * 8));

  const f16x8 z8 = {};
  const f16x2 z2 = {};

  __syncthreads();

  float res[8];  // per-jt partial (static-indexed under full unroll -> regs)

#pragma unroll
  for (int jt = 0; jt < 8; ++jt) {
    // h1 B-frags: B[k = 32c + quad*8 + jj][n = l4] = relu(u'[k] + v_j[k])
    // swizzled read matches the staged layout ((l4&7) == (row&7))
    f16x8 hb[4];
#pragma unroll
    for (int c = 0; c < 4; ++c) {
      const uint4 v = *(const uint4*)((const char*)Vs + (jt * 16 + l4) * 256 +
                                      ((c * 64 + quad * 16) ^ ((l4 & 7) << 4)));
      hb[c] = __builtin_elementwise_max(__builtin_bit_cast(f16x8, v) + uf[c], z8);
    }

    // layer2 MFMA; first k-slice consumes b2f directly as C (no acc init).
    f32x4 acc[4];
    __builtin_amdgcn_s_setprio(1);
#pragma unroll
    for (int tp = 0; tp < 4; ++tp)
      acc[tp] = __builtin_amdgcn_mfma_f32_16x16x32_f16(w2r[tp][0], hb[0], b2f[tp], 0, 0, 0);
#pragma unroll
    for (int c = 1; c < 4; ++c)
#pragma unroll
      for (int tp = 0; tp < 4; ++tp)
        acc[tp] = __builtin_amdgcn_mfma_f32_16x16x32_f16(w2r[tp][c], hb[c], acc[tp], 0, 0, 0);
    __builtin_amdgcn_s_setprio(0);

    // layer3 in-lane partial: relu + fp16 dot (b2 already in acc)
    float t0 = 0.f, t1 = 0.f, t2 = 0.f, t3 = 0.f;
#pragma unroll
    for (int tp = 0; tp < 4; tp += 2) {
      f16x2 p0 = __builtin_elementwise_max(cvt_pk(acc[tp][0], acc[tp][1]), z2);
      f16x2 p1 = __builtin_elementwise_max(cvt_pk(acc[tp][2], acc[tp][3]), z2);
      t0 = __builtin_amdgcn_fdot2(p0, w3p[tp][0], t0, false);
      t1 = __builtin_amdgcn_fdot2(p1, w3p[tp][1], t1, false);
      f16x2 q0 = __builtin_elementwise_max(cvt_pk(acc[tp + 1][0], acc[tp + 1][1]), z2);
      f16x2 q1 = __builtin_elementwise_max(cvt_pk(acc[tp + 1][2], acc[tp + 1][3]), z2);
      t2 = __builtin_amdgcn_fdot2(q0, w3p[tp + 1][0], t2, false);
      t3 = __builtin_amdgcn_fdot2(q1, w3p[tp + 1][1], t3, false);
    }
    res[jt] = (t0 + t1) + (t2 + t3);
  }

  __syncthreads();  // all Vs reads complete -> safe to overlay

  // overlay reduction buffer on Vs: pls[th][il][jt][quad][l4]
  {
    float* pls = (float*)Vs;
    const int base = ((th * 2 + il) * 8) * 64 + quad * 16 + l4;
#pragma unroll
    for (int jt = 0; jt < 8; ++jt) pls[base + jt * 64] = res[jt];
  }

  __syncthreads();

  {
    const float* pls = (const float*)Vs;
    const int ril = tid >> 7, rjt = (tid >> 4) & 7, rl4 = tid & 15;
    float sum = b3[0];
#pragma unroll
    for (int h = 0; h < 2; ++h)
#pragma unroll
      for (int q = 0; q < 4; ++q)
        sum += pls[((h * 2 + ril) * 8 + rjt) * 64 + q * 16 + rl4];
    const int ri = i0 + ril;
    const int j = j0 + rjt * 16 + rl4;
    if (j != ri) {
      const int p = (b * N_ + ri) * PPI + (j < ri ? j : j - 1);
      out[p] = sum;
    }
  }
}

extern "C" void kernel_launch(void* const* d_in, const int* in_sizes, int n_in,
                              void* d_out, int out_size, void* d_ws, size_t ws_size,
                              hipStream_t stream) {
  const float* feat = (const float*)d_in[0];
  const float* W1 = (const float*)d_in[1];
  const float* b1 = (const float*)d_in[2];
  const float* W2 = (const float*)d_in[3];
  const float* b2 = (const float*)d_in[4];
  const float* W3 = (const float*)d_in[5];
  const float* b3 = (const float*)d_in[6];

  uint16_t* U = (uint16_t*)d_ws;                 // B*N*R fp16 = 512 KiB
  uint16_t* V = U + (size_t)B_ * N_ * R_;        // 512 KiB
  uint16_t* w2f = V + (size_t)B_ * N_ * R_;      // 32 KiB

  prep_all<<<64 + 64, 256, 0, stream>>>(feat, W1, b1, W2, U, V, w2f);
  relnet_main<<<B_ * (N_ / 2) * (N_ / TJ), 256, 0, stream>>>(U, V, w2f, b2, W3, b3,
                                                             (float*)d_out);
}